// Round 2
// baseline (280.498 us; speedup 1.0000x reference)
//
#include <hip/hip_runtime.h>
#include <math.h>

#define NPTS 100000
#define NVERTS 6890
#define NJ 24
#define CHUNK 3445  // NVERTS/2; LDS = 3445*16 = 55120 B -> 2 blocks/CU

// ---------------- Kernel 1: f32 NN scan, bit-matching the reference formula ----------------
// Reference (numpy/jax f32):
//   d2 = sum(x*x) - 2*(x @ v.T) + sum(v*v)
// evaluated as: d2 = ( xsq - 2*G ) + vsq, with
//   G   = K=3 GEMM dot, ascending-k FMA: g = x0*vx; g = fma(x1,vy,g); g = fma(x2,vz,g)
//   vsq = (vx*vx + vy*vy) + vz*vz   (np.sum over axis=-1, sequential for 3 elems)
//   xsq = (x0*x0 + x1*x1) + x2*x2
// argmin with first-index tie-break (np.argmin). fp contract OFF so hipcc's
// -ffp-contract=fast cannot re-associate the plain mul/adds.
__global__ __launch_bounds__(256, 2) void nn_kernel(
    const float* __restrict__ xyz,
    const float* __restrict__ verts,
    int* __restrict__ idx_out)
{
#pragma clang fp contract(off)
    __shared__ float4 vlds[CHUNK];
    const int tid = threadIdx.x;
    const int p = blockIdx.x * 256 + tid;
    const int pc = (p < NPTS) ? p : (NPTS - 1);

    const float x0 = xyz[pc * 3 + 0];
    const float x1 = xyz[pc * 3 + 1];
    const float x2 = xyz[pc * 3 + 2];
    const float xsq = (x0 * x0 + x1 * x1) + x2 * x2;

    float best = 1e30f;
    int bidx = 0;

    for (int c = 0; c < 2; ++c) {
        const int base = c * CHUNK;
        for (int i = tid; i < CHUNK; i += 256) {
            const int v = base + i;
            const float vx = verts[v * 3 + 0];
            const float vy = verts[v * 3 + 1];
            const float vz = verts[v * 3 + 2];
            const float a = vx * vx;
            const float b = vy * vy;
            const float cz = vz * vz;
            const float vsq = (a + b) + cz;   // matches np.sum(v*v, -1)
            vlds[i] = make_float4(vx, vy, vz, vsq);
        }
        __syncthreads();

        #pragma unroll 4
        for (int i = 0; i < CHUNK; ++i) {
            const float4 v = vlds[i];  // uniform-address broadcast ds_read_b128
            float g = x0 * v.x;        // == fma(x0,vx,0): rnd(x0*vx), BLAS acc init
            g = fmaf(x1, v.y, g);      // ascending-k FMA chain (K=3 GEMM microkernel)
            g = fmaf(x2, v.z, g);
            // xsq - 2*G: 2*G is exact (x2 scaling), so fmaf(-2,G,xsq) == rnd(xsq-2G)
            const float t = fmaf(-2.0f, g, xsq);
            const float d2 = t + v.w;  // single rounding, matches (A-B)+C
            const bool lt = (d2 < best);  // strict <: first index wins exact ties
            best = lt ? d2 : best;
            bidx = lt ? (base + i) : bidx;
        }
        __syncthreads();
    }

    if (p < NPTS) idx_out[p] = bidx;
}

// ---------------- Kernel 2: per-point skinning + quaternion + outputs ----------------
__global__ __launch_bounds__(256) void apply_kernel(
    const float* __restrict__ xyz,
    const float* __restrict__ rot,
    const float* __restrict__ sw,
    const float* __restrict__ tm,
    const int* __restrict__ idx_arr,
    float* __restrict__ out)
{
    __shared__ float tl[NJ * 16];
    const int tid = threadIdx.x;
    for (int i = tid; i < NJ * 16; i += 256) tl[i] = tm[i];
    __syncthreads();

    const int p = blockIdx.x * 256 + tid;
    if (p >= NPTS) return;

    const int vi = idx_arr[p];
    const float4* w4 = reinterpret_cast<const float4*>(sw + (size_t)vi * NJ);

    float T[16];
    #pragma unroll
    for (int i = 0; i < 16; ++i) T[i] = 0.0f;

    #pragma unroll
    for (int jq = 0; jq < NJ / 4; ++jq) {
        const float4 wv = w4[jq];
        const float wj[4] = { wv.x, wv.y, wv.z, wv.w };
        #pragma unroll
        for (int k = 0; k < 4; ++k) {
            const int j = jq * 4 + k;
            #pragma unroll
            for (int i = 0; i < 16; ++i)
                T[i] = fmaf(wj[k], tl[j * 16 + i], T[i]);
        }
    }

    // quaternion -> rotation matrix
    const float4 q = reinterpret_cast<const float4*>(rot)[p];
    float qr = q.x, qx = q.y, qy = q.z, qz = q.w;
    const float inv = 1.0f / sqrtf(qr * qr + qx * qx + qy * qy + qz * qz);
    qr *= inv; qx *= inv; qy *= inv; qz *= inv;
    float R[9];
    R[0] = 1.0f - 2.0f * (qy * qy + qz * qz);
    R[1] = 2.0f * (qx * qy - qr * qz);
    R[2] = 2.0f * (qx * qz + qr * qy);
    R[3] = 2.0f * (qx * qy + qr * qz);
    R[4] = 1.0f - 2.0f * (qx * qx + qz * qz);
    R[5] = 2.0f * (qy * qz - qr * qx);
    R[6] = 2.0f * (qx * qz - qr * qy);
    R[7] = 2.0f * (qy * qz + qr * qx);
    R[8] = 1.0f - 2.0f * (qx * qx + qy * qy);

    const float x0 = xyz[p * 3 + 0];
    const float x1 = xyz[p * 3 + 1];
    const float x2 = xyz[p * 3 + 2];

    // x_bar: out[0 .. 300000)
    #pragma unroll
    for (int i = 0; i < 3; ++i) {
        out[p * 3 + i] = fmaf(T[i * 4 + 0], x0,
                          fmaf(T[i * 4 + 1], x1,
                           fmaf(T[i * 4 + 2], x2, T[i * 4 + 3])));
    }

    // rotation_bar: out[300000 .. 1200000), [p][i][k] = sum_j T[i*4+j]*R[j*3+k]
    float* rb = out + 300000 + (size_t)p * 9;
    #pragma unroll
    for (int i = 0; i < 3; ++i) {
        #pragma unroll
        for (int k = 0; k < 3; ++k) {
            rb[i * 3 + k] = fmaf(T[i * 4 + 0], R[0 * 3 + k],
                             fmaf(T[i * 4 + 1], R[1 * 3 + k],
                                  T[i * 4 + 2] * R[2 * 3 + k]));
        }
    }

    // T_fwd: out[1200000 .. 2800000)
    float* tb = out + 1200000 + (size_t)p * 16;
    #pragma unroll
    for (int i = 0; i < 16; ++i) tb[i] = T[i];
}

extern "C" void kernel_launch(void* const* d_in, const int* in_sizes, int n_in,
                              void* d_out, int out_size, void* d_ws, size_t ws_size,
                              hipStream_t stream) {
    const float* xyz   = (const float*)d_in[0];
    const float* rot   = (const float*)d_in[1];
    const float* verts = (const float*)d_in[2];
    const float* sw    = (const float*)d_in[3];
    const float* tm    = (const float*)d_in[4];
    float* out = (float*)d_out;

    int* idx = (int*)d_ws;  // per-point NN index (fully overwritten each call)

    const int grid = (NPTS + 255) / 256;  // 391
    nn_kernel<<<grid, 256, 0, stream>>>(xyz, verts, idx);
    apply_kernel<<<grid, 256, 0, stream>>>(xyz, rot, sw, tm, idx, out);
}

// Round 3
// 145.081 us; speedup vs baseline: 1.9334x; 1.9334x over previous
//
#include <hip/hip_runtime.h>
#include <math.h>

#define NPTS 100000
#define NVERTS 6890
#define NJ 24

#define TPB 256
#define PPT 4                       // points per thread
#define PPB (TPB * PPT)             // 1024 points per block
#define NPB ((NPTS + PPB - 1) / PPB)  // 98 point-blocks
#define NCH 16                      // vertex chunks
#define VCH ((NVERTS + NCH - 1) / NCH)  // 431 verts/chunk, 6896 B LDS

// ---------------- Kernel 1: f32 NN scan, bit-matching the reference formula ----------------
// d2 = (xsq - 2*G) + vsq with G = ascending-k FMA dot (BLAS K=3), vsq = (vx^2+vy^2)+vz^2.
// Bit-exact vs numpy f32 -> argmin matches np.argmin (strict <, first index ties).
// Grid: x = point-block (98), y = vertex chunk (16). Partial (best,idx) merged via
// packed u64 atomicMin: (f32_bits(best)<<32)|idx -- unsigned order == (d2, idx) lexicographic
// for positive d2, reproducing first-index tie-break globally.
__global__ __launch_bounds__(256, 4) void nn_kernel(
    const float* __restrict__ xyz,
    const float* __restrict__ verts,
    unsigned long long* __restrict__ best_ws)
{
#pragma clang fp contract(off)
    __shared__ float4 vlds[VCH];
    const int tid = threadIdx.x;
    const int vbase = blockIdx.y * VCH;
    const int vcnt = min(VCH, NVERTS - vbase);  // 431 (last chunk: 425)

    for (int i = tid; i < vcnt; i += TPB) {
        const int v = vbase + i;
        const float vx = verts[v * 3 + 0];
        const float vy = verts[v * 3 + 1];
        const float vz = verts[v * 3 + 2];
        vlds[i] = make_float4(vx, vy, vz, (vx * vx + vy * vy) + vz * vz);
    }
    __syncthreads();

    const int p0 = blockIdx.x * PPB + tid;
    float px[PPT], py[PPT], pz[PPT], xsq[PPT], best[PPT];
    int bidx[PPT];
    #pragma unroll
    for (int k = 0; k < PPT; ++k) {
        const int p = p0 + k * TPB;
        const int pc = (p < NPTS) ? p : (NPTS - 1);
        px[k] = xyz[pc * 3 + 0];
        py[k] = xyz[pc * 3 + 1];
        pz[k] = xyz[pc * 3 + 2];
        xsq[k] = (px[k] * px[k] + py[k] * py[k]) + pz[k] * pz[k];
        best[k] = 1e30f;
        bidx[k] = 0;
    }

    #pragma unroll 2
    for (int i = 0; i < vcnt; ++i) {
        const float4 v = vlds[i];  // uniform-address broadcast, conflict-free
        #pragma unroll
        for (int k = 0; k < PPT; ++k) {
            float g = px[k] * v.x;          // rnd(x0*vx)
            g = fmaf(py[k], v.y, g);        // ascending-k FMA chain
            g = fmaf(pz[k], v.z, g);
            const float t = fmaf(-2.0f, g, xsq[k]);  // == rnd(xsq - 2G), 2G exact
            const float d2 = t + v.w;                // rnd(t + vsq)
            const bool lt = (d2 < best[k]);          // strict <: first index on ties
            best[k] = lt ? d2 : best[k];
            bidx[k] = lt ? (vbase + i) : bidx[k];
        }
    }

    #pragma unroll
    for (int k = 0; k < PPT; ++k) {
        const int p = p0 + k * TPB;
        if (p < NPTS) {
            const unsigned long long pk =
                ((unsigned long long)__float_as_uint(best[k]) << 32) |
                (unsigned int)bidx[k];
            atomicMin(&best_ws[p], pk);
        }
    }
}

// ---------------- Kernel 2: per-point skinning + quaternion + outputs ----------------
__global__ __launch_bounds__(256) void apply_kernel(
    const float* __restrict__ xyz,
    const float* __restrict__ rot,
    const float* __restrict__ sw,
    const float* __restrict__ tm,
    const unsigned long long* __restrict__ best_ws,
    float* __restrict__ out)
{
    __shared__ float tl[NJ * 16];
    const int tid = threadIdx.x;
    for (int i = tid; i < NJ * 16; i += 256) tl[i] = tm[i];
    __syncthreads();

    const int p = blockIdx.x * 256 + tid;
    if (p >= NPTS) return;

    const int vi = (int)(best_ws[p] & 0xFFFFFFFFull);
    const float4* w4 = reinterpret_cast<const float4*>(sw + (size_t)vi * NJ);

    float T[16];
    #pragma unroll
    for (int i = 0; i < 16; ++i) T[i] = 0.0f;

    #pragma unroll
    for (int jq = 0; jq < NJ / 4; ++jq) {
        const float4 wv = w4[jq];
        const float wj[4] = { wv.x, wv.y, wv.z, wv.w };
        #pragma unroll
        for (int k = 0; k < 4; ++k) {
            const int j = jq * 4 + k;
            #pragma unroll
            for (int i = 0; i < 16; ++i)
                T[i] = fmaf(wj[k], tl[j * 16 + i], T[i]);
        }
    }

    // quaternion -> rotation matrix
    const float4 q = reinterpret_cast<const float4*>(rot)[p];
    float qr = q.x, qx = q.y, qy = q.z, qz = q.w;
    const float inv = 1.0f / sqrtf(qr * qr + qx * qx + qy * qy + qz * qz);
    qr *= inv; qx *= inv; qy *= inv; qz *= inv;
    float R[9];
    R[0] = 1.0f - 2.0f * (qy * qy + qz * qz);
    R[1] = 2.0f * (qx * qy - qr * qz);
    R[2] = 2.0f * (qx * qz + qr * qy);
    R[3] = 2.0f * (qx * qy + qr * qz);
    R[4] = 1.0f - 2.0f * (qx * qx + qz * qz);
    R[5] = 2.0f * (qy * qz - qr * qx);
    R[6] = 2.0f * (qx * qz - qr * qy);
    R[7] = 2.0f * (qy * qz + qr * qx);
    R[8] = 1.0f - 2.0f * (qx * qx + qy * qy);

    const float x0 = xyz[p * 3 + 0];
    const float x1 = xyz[p * 3 + 1];
    const float x2 = xyz[p * 3 + 2];

    // x_bar: out[0 .. 300000)
    #pragma unroll
    for (int i = 0; i < 3; ++i) {
        out[p * 3 + i] = fmaf(T[i * 4 + 0], x0,
                          fmaf(T[i * 4 + 1], x1,
                           fmaf(T[i * 4 + 2], x2, T[i * 4 + 3])));
    }

    // rotation_bar: out[300000 .. 1200000), [p][i][k] = sum_j T[i*4+j]*R[j*3+k]
    float* rb = out + 300000 + (size_t)p * 9;
    #pragma unroll
    for (int i = 0; i < 3; ++i) {
        #pragma unroll
        for (int k = 0; k < 3; ++k) {
            rb[i * 3 + k] = fmaf(T[i * 4 + 0], R[0 * 3 + k],
                             fmaf(T[i * 4 + 1], R[1 * 3 + k],
                                  T[i * 4 + 2] * R[2 * 3 + k]));
        }
    }

    // T_fwd: out[1200000 .. 2800000)
    float* tb = out + 1200000 + (size_t)p * 16;
    #pragma unroll
    for (int i = 0; i < 16; ++i) tb[i] = T[i];
}

extern "C" void kernel_launch(void* const* d_in, const int* in_sizes, int n_in,
                              void* d_out, int out_size, void* d_ws, size_t ws_size,
                              hipStream_t stream) {
    const float* xyz   = (const float*)d_in[0];
    const float* rot   = (const float*)d_in[1];
    const float* verts = (const float*)d_in[2];
    const float* sw    = (const float*)d_in[3];
    const float* tm    = (const float*)d_in[4];
    float* out = (float*)d_out;

    unsigned long long* best_ws = (unsigned long long*)d_ws;  // NPTS packed (d2,idx)

    // init packed mins to 0xFFFF... (max u64) each call -- capture-safe async memset
    hipMemsetAsync(d_ws, 0xFF, NPTS * sizeof(unsigned long long), stream);

    dim3 grid(NPB, NCH);  // 98 x 16 = 1568 blocks
    nn_kernel<<<grid, TPB, 0, stream>>>(xyz, verts, best_ws);
    apply_kernel<<<(NPTS + 255) / 256, 256, 0, stream>>>(xyz, rot, sw, tm, best_ws, out);
}

// Round 4
// 143.398 us; speedup vs baseline: 1.9561x; 1.0117x over previous
//
#include <hip/hip_runtime.h>
#include <math.h>

#define NPTS 100000
#define NVERTS 6890
#define NJ 24

#define TPB 256
#define PPT 8                         // points per thread (8 independent argmin chains)
#define PPB (TPB * PPT)               // 2048 points per block
#define NPB ((NPTS + PPB - 1) / PPB)  // 49 point-blocks
#define NCH 32                        // vertex chunks
#define VCH ((NVERTS + NCH - 1) / NCH)  // 216 verts/chunk, 3456 B LDS

// ---------------- Kernel 1: f32 NN scan, bit-matching the reference formula ----------------
// d2 = (xsq - 2*G) + vsq with G = ascending-k FMA dot (BLAS K=3), vsq = (vx^2+vy^2)+vz^2.
// Bit-exact vs numpy f32 -> argmin matches np.argmin (strict <, first index ties).
// Grid: x = point-block (49), y = vertex chunk (32). Partials merged via packed u64
// atomicMin: (f32_bits(d2)<<32)|idx -- unsigned order == (d2, idx) lexicographic for
// positive d2, reproducing np.argmin's first-index tie-break globally.
__global__ __launch_bounds__(256, 6) void nn_kernel(
    const float* __restrict__ xyz,
    const float* __restrict__ verts,
    unsigned long long* __restrict__ best_ws)
{
#pragma clang fp contract(off)
    __shared__ float4 vlds[VCH];
    const int tid = threadIdx.x;
    const int vbase = blockIdx.y * VCH;
    const int vcnt = min(VCH, NVERTS - vbase);  // 216 (last chunk: 194)

    for (int i = tid; i < vcnt; i += TPB) {
        const int v = vbase + i;
        const float vx = verts[v * 3 + 0];
        const float vy = verts[v * 3 + 1];
        const float vz = verts[v * 3 + 2];
        vlds[i] = make_float4(vx, vy, vz, (vx * vx + vy * vy) + vz * vz);
    }
    __syncthreads();

    const int p0 = blockIdx.x * PPB + tid;
    float px[PPT], py[PPT], pz[PPT], xsq[PPT], best[PPT];
    int bidx[PPT];
    #pragma unroll
    for (int k = 0; k < PPT; ++k) {
        const int p = p0 + k * TPB;
        const int pc = (p < NPTS) ? p : (NPTS - 1);
        px[k] = xyz[pc * 3 + 0];
        py[k] = xyz[pc * 3 + 1];
        pz[k] = xyz[pc * 3 + 2];
        xsq[k] = (px[k] * px[k] + py[k] * py[k]) + pz[k] * pz[k];
        best[k] = 1e30f;
        bidx[k] = 0;
    }

    // 2-stage software pipeline: issue next vertex's ds_read before computing current.
    float4 vc = vlds[0];
    #pragma unroll 1
    for (int i = 0; i < vcnt; ++i) {
        const float4 vn = vlds[(i + 1 < vcnt) ? (i + 1) : i];  // prefetch (uniform bcast)
        const int vidx = vbase + i;
        #pragma unroll
        for (int k = 0; k < PPT; ++k) {
            float g = px[k] * vc.x;          // rnd(x0*vx)
            g = fmaf(py[k], vc.y, g);        // ascending-k FMA chain
            g = fmaf(pz[k], vc.z, g);
            const float t = fmaf(-2.0f, g, xsq[k]);  // == rnd(xsq - 2G), 2G exact
            const float d2 = t + vc.w;               // rnd(t + vsq)
            const bool lt = (d2 < best[k]);          // strict <: first index on ties
            best[k] = lt ? d2 : best[k];
            bidx[k] = lt ? vidx : bidx[k];
        }
        vc = vn;
    }

    #pragma unroll
    for (int k = 0; k < PPT; ++k) {
        const int p = p0 + k * TPB;
        if (p < NPTS) {
            const unsigned long long pk =
                ((unsigned long long)__float_as_uint(best[k]) << 32) |
                (unsigned int)bidx[k];
            atomicMin(&best_ws[p], pk);
        }
    }
}

// ---------------- Kernel 2: per-point skinning + quaternion + outputs ----------------
__global__ __launch_bounds__(256) void apply_kernel(
    const float* __restrict__ xyz,
    const float* __restrict__ rot,
    const float* __restrict__ sw,
    const float* __restrict__ tm,
    const unsigned long long* __restrict__ best_ws,
    float* __restrict__ out)
{
    __shared__ float tl[NJ * 16];
    const int tid = threadIdx.x;
    for (int i = tid; i < NJ * 16; i += 256) tl[i] = tm[i];
    __syncthreads();

    const int p = blockIdx.x * 256 + tid;
    if (p >= NPTS) return;

    const int vi = (int)(best_ws[p] & 0xFFFFFFFFull);
    const float4* w4 = reinterpret_cast<const float4*>(sw + (size_t)vi * NJ);

    float T[16];
    #pragma unroll
    for (int i = 0; i < 16; ++i) T[i] = 0.0f;

    #pragma unroll
    for (int jq = 0; jq < NJ / 4; ++jq) {
        const float4 wv = w4[jq];
        const float wj[4] = { wv.x, wv.y, wv.z, wv.w };
        #pragma unroll
        for (int k = 0; k < 4; ++k) {
            const int j = jq * 4 + k;
            #pragma unroll
            for (int i = 0; i < 16; ++i)
                T[i] = fmaf(wj[k], tl[j * 16 + i], T[i]);
        }
    }

    // quaternion -> rotation matrix
    const float4 q = reinterpret_cast<const float4*>(rot)[p];
    float qr = q.x, qx = q.y, qy = q.z, qz = q.w;
    const float inv = 1.0f / sqrtf(qr * qr + qx * qx + qy * qy + qz * qz);
    qr *= inv; qx *= inv; qy *= inv; qz *= inv;
    float R[9];
    R[0] = 1.0f - 2.0f * (qy * qy + qz * qz);
    R[1] = 2.0f * (qx * qy - qr * qz);
    R[2] = 2.0f * (qx * qz + qr * qy);
    R[3] = 2.0f * (qx * qy + qr * qz);
    R[4] = 1.0f - 2.0f * (qx * qx + qz * qz);
    R[5] = 2.0f * (qy * qz - qr * qx);
    R[6] = 2.0f * (qx * qz - qr * qy);
    R[7] = 2.0f * (qy * qz + qr * qx);
    R[8] = 1.0f - 2.0f * (qx * qx + qy * qy);

    const float x0 = xyz[p * 3 + 0];
    const float x1 = xyz[p * 3 + 1];
    const float x2 = xyz[p * 3 + 2];

    // x_bar: out[0 .. 300000)
    #pragma unroll
    for (int i = 0; i < 3; ++i) {
        out[p * 3 + i] = fmaf(T[i * 4 + 0], x0,
                          fmaf(T[i * 4 + 1], x1,
                           fmaf(T[i * 4 + 2], x2, T[i * 4 + 3])));
    }

    // rotation_bar: out[300000 .. 1200000), [p][i][k] = sum_j T[i*4+j]*R[j*3+k]
    float* rb = out + 300000 + (size_t)p * 9;
    #pragma unroll
    for (int i = 0; i < 3; ++i) {
        #pragma unroll
        for (int k = 0; k < 3; ++k) {
            rb[i * 3 + k] = fmaf(T[i * 4 + 0], R[0 * 3 + k],
                             fmaf(T[i * 4 + 1], R[1 * 3 + k],
                                  T[i * 4 + 2] * R[2 * 3 + k]));
        }
    }

    // T_fwd: out[1200000 .. 2800000)
    float* tb = out + 1200000 + (size_t)p * 16;
    #pragma unroll
    for (int i = 0; i < 16; ++i) tb[i] = T[i];
}

extern "C" void kernel_launch(void* const* d_in, const int* in_sizes, int n_in,
                              void* d_out, int out_size, void* d_ws, size_t ws_size,
                              hipStream_t stream) {
    const float* xyz   = (const float*)d_in[0];
    const float* rot   = (const float*)d_in[1];
    const float* verts = (const float*)d_in[2];
    const float* sw    = (const float*)d_in[3];
    const float* tm    = (const float*)d_in[4];
    float* out = (float*)d_out;

    unsigned long long* best_ws = (unsigned long long*)d_ws;  // NPTS packed (d2,idx)

    // init packed mins to 0xFFFF... (max u64) each call -- capture-safe async memset
    hipMemsetAsync(d_ws, 0xFF, NPTS * sizeof(unsigned long long), stream);

    dim3 grid(NPB, NCH);  // 49 x 32 = 1568 blocks
    nn_kernel<<<grid, TPB, 0, stream>>>(xyz, verts, best_ws);
    apply_kernel<<<(NPTS + 255) / 256, 256, 0, stream>>>(xyz, rot, sw, tm, best_ws, out);
}